// Round 14
// baseline (545.095 us; speedup 1.0000x reference)
//
#include <hip/hip_runtime.h>

// VQ-VAE vector quantizer, round 14: pure-VALU exact-fp32, zero-LDS hot loop, fixed.
// R13's design failed on two compiler/config defects, not the theory: (a) launch_bounds(128)
// let the compiler pick VGPR=48 -> x[64] never register-resident (rematerialized loads);
// (b) 1 point/thread = 65536 threads = 1 wave/SIMD, no latency cover. Fix:
//   - thread (p,q) owns point p x code-quarter [256q,256q+256): 262144 threads = 4 waves/SIMD
//   - __launch_bounds__(512,4): VGPR cap 128; live set ~100 (x 64 + acc 16 + misc) fits
//   - e rows + hsq are wave-uniform addresses -> s_load (SMEM pipe); x loads coalesced
// Model: FMA issue floor 131k cyc/SIMD = 54.6us; +6% tracking; target 65-80us at 70-85%
// VALUBusy. Distances d = 0.5||e||^2 - x.e exact fp32 (the formula all passing rounds used).
// out (fp32 concat): [ loss(1) | quantized NCHW (4194304) | indices as float (65536) ]

#define DIMS   64
#define HW     4096
#define NPTS   65536
#define NCODES 1024
#define NPB    128                 // points per block (512 threads = 128 pts x 4 quarters)
#define QOFF   1
#define IOFF   (1 + NPTS * DIMS)

typedef unsigned int uint;

// ---- prep: Et[d][k] = emb[k][d] (transposed fp32), hsq[k] = 0.5||e_k||^2, zero out[0]
__global__ void vq_prep(const float* __restrict__ emb, float* __restrict__ Et,
                        float* __restrict__ hsq, float* __restrict__ out)
{
    const int t = blockIdx.x * 256 + threadIdx.x;      // 0..16383
    if (t == 0) out[0] = 0.f;
    const int k = t & 1023, dg = t >> 10;              // code, dim-group of 4
    float4 v = ((const float4*)emb)[k * 16 + dg];      // emb[k][4dg..4dg+3]
    Et[(dg * 4 + 0) * 1024 + k] = v.x;                 // stores coalesced over k
    Et[(dg * 4 + 1) * 1024 + k] = v.y;
    Et[(dg * 4 + 2) * 1024 + k] = v.z;
    Et[(dg * 4 + 3) * 1024 + k] = v.w;
    if (t < NCODES) {
        const float4* r = (const float4*)(emb + (size_t)t * DIMS);
        float s = 0.f;
        #pragma unroll
        for (int i = 0; i < 16; ++i) {
            float4 e = r[i];
            s = fmaf(e.x, e.x, s); s = fmaf(e.y, e.y, s);
            s = fmaf(e.z, e.z, s); s = fmaf(e.w, e.w, s);
        }
        hsq[t] = 0.5f * s;
    }
}

__launch_bounds__(512, 4)
__global__ void vq_main(const float* __restrict__ in, const float* __restrict__ emb,
                        const float* __restrict__ Et, const float* __restrict__ hsqw,
                        float* __restrict__ out)
{
    __shared__ float cv[4][NPB];                       // per-quarter candidates
    __shared__ int   ci[4][NPB];
    __shared__ float lred[8];

    const int tid = threadIdx.x;
    const int lane = tid & 63, w = tid >> 6;
    const int p = tid & 127, q = tid >> 7;             // point-in-block, code-quarter
    const int n0 = blockIdx.x * NPB;
    const int b = n0 >> 12, off = n0 & 4095;           // 128 | 4096: never crosses a batch
    const float* xbase = in + (size_t)b * (DIMS * HW) + off;
    const float* xp = xbase + p;

    // ---- x entirely in registers (static indices; 64 VGPRs, cap 128 leaves room)
    float x[64];
    #pragma unroll
    for (int d = 0; d < 64; ++d) x[d] = xp[d * HW];    // coalesced over the 64 lanes (=points)

    float v1 = 1e30f; int i1 = 0;

    // ---- this thread's 256 codes in 16 chunks of 16; e/hsq addresses wave-uniform (s_load)
    const int kq = q * 256;
    for (int ch = 0; ch < 16; ++ch) {
        const int k0 = kq + ch * 16;
        float acc[16];
        #pragma unroll
        for (int j = 0; j < 16; ++j) acc[j] = 0.f;

        #pragma unroll
        for (int d = 0; d < 64; ++d) {                 // 16 independent FMA chains
            const float4* er = (const float4*)(Et + d * 1024 + k0);
            float4 e0 = er[0], e1 = er[1], e2 = er[2], e3 = er[3];
            const float xd = x[d];
            acc[ 0] = fmaf(xd, e0.x, acc[ 0]); acc[ 1] = fmaf(xd, e0.y, acc[ 1]);
            acc[ 2] = fmaf(xd, e0.z, acc[ 2]); acc[ 3] = fmaf(xd, e0.w, acc[ 3]);
            acc[ 4] = fmaf(xd, e1.x, acc[ 4]); acc[ 5] = fmaf(xd, e1.y, acc[ 5]);
            acc[ 6] = fmaf(xd, e1.z, acc[ 6]); acc[ 7] = fmaf(xd, e1.w, acc[ 7]);
            acc[ 8] = fmaf(xd, e2.x, acc[ 8]); acc[ 9] = fmaf(xd, e2.y, acc[ 9]);
            acc[10] = fmaf(xd, e2.z, acc[10]); acc[11] = fmaf(xd, e2.w, acc[11]);
            acc[12] = fmaf(xd, e3.x, acc[12]); acc[13] = fmaf(xd, e3.y, acc[13]);
            acc[14] = fmaf(xd, e3.z, acc[14]); acc[15] = fmaf(xd, e3.w, acc[15]);
        }
        #pragma unroll
        for (int j = 0; j < 16; ++j) {                 // ascending k, strict <: first-min kept
            float dv = hsqw[k0 + j] - acc[j];
            if (dv < v1) { v1 = dv; i1 = k0 + j; }
        }
    }
    cv[q][p] = v1; ci[q][p] = i1;
    __syncthreads();

    // ---- merge the 4 quarters per point (ascending q = ascending code range)
    if (tid < NPB) {
        float bv = cv[0][tid]; int bi = ci[0][tid];
        #pragma unroll
        for (int qq = 1; qq < 4; ++qq) {
            float ov = cv[qq][tid]; int oi = ci[qq][tid];
            if (ov < bv) { bv = ov; bi = oi; }         // strict: earlier quarter wins ties
        }
        ci[0][tid] = bi;
    }
    __syncthreads();

    // ---- outputs: index, quantized gather-write, loss (512 threads: 16 dims each)
    {
        const int bi = ci[0][p];
        if (q == 0) out[IOFF + n0 + p] = (float)bi;
        const float* e = emb + (size_t)bi * DIMS;
        float* oq = out + QOFF + (size_t)b * (DIMS * HW) + off + p;
        float ls = 0.f;
        #pragma unroll
        for (int d0 = 0; d0 < 16; ++d0) {
            const int d = q * 16 + d0;
            float ev = e[d];                           // gather (L1/L2-hot 256 KB table)
            float df = ev - x[d];                      // x still register-resident
            ls = fmaf(df, df, ls);
            oq[d * HW] = ev;                           // coalesced over point-threads
        }
        #pragma unroll
        for (int st = 32; st; st >>= 1) ls += __shfl_down(ls, st);
        if (lane == 0) lred[w] = ls;
    }
    __syncthreads();
    if (tid == 0) {
        float s = 0.f;
        #pragma unroll
        for (int i = 0; i < 8; ++i) s += lred[i];
        atomicAdd(out, s * (0.25f / (float)(NPTS * DIMS)));
    }
}

extern "C" void kernel_launch(void* const* d_in, const int* in_sizes, int n_in,
                              void* d_out, int out_size, void* d_ws, size_t ws_size,
                              hipStream_t stream) {
    const float* in  = (const float*)d_in[0];
    const float* emb = (const float*)d_in[1];
    float* out = (float*)d_out;
    float* Et  = (float*)d_ws;                         // 262144 B (transposed table)
    float* hsq = (float*)((char*)d_ws + 262144);       // 4096 B
    (void)in_sizes; (void)n_in; (void)out_size; (void)ws_size;

    vq_prep<<<64, 256, 0, stream>>>(emb, Et, hsq, out);   // also zeroes out[0]
    vq_main<<<NPTS / NPB, 512, 0, stream>>>(in, emb, Et, hsq, out);
}

// Round 15
// 218.297 us; speedup vs baseline: 2.4970x; 2.4970x over previous
//
#include <hip/hip_runtime.h>

// VQ-VAE vector quantizer, round 15: pure-VALU exact-fp32 — register-residency fixed.
// R13/R14 failures were both x[64]-spill sabotage: R13 single-arg launch_bounds let the
// occupancy heuristic pick VGPR=48 (remat from global); R14's epilogue x[q*16+d0] dynamic
// index forced the array to scratch (WRITE 83MB). This round:
//   - NO dynamic indexing anywhere (epilogue re-reads x from global, 16 coalesced loads)
//   - __launch_bounds__(512,4): VGPR cap 128; live set ~110 (x 64 + acc 16 + e 16 + misc)
//   - readfirstlane on quarter base -> SGPR base -> e/hsq scalarize to s_load (SMEM pipe)
// Thread (p,q): point p, code-quarter [256q,256q+256). 512 thr/block, 512 blocks,
// 2 blocks/CU = 4 waves/SIMD. Model: 131k FMA cyc/SIMD = 54.6us floor; target 65-80us.
// out (fp32 concat): [ loss(1) | quantized NCHW (4194304) | indices as float (65536) ]

#define DIMS   64
#define HW     4096
#define NPTS   65536
#define NCODES 1024
#define NPB    128                 // points per block (512 threads = 128 pts x 4 quarters)
#define QOFF   1
#define IOFF   (1 + NPTS * DIMS)

typedef unsigned int uint;

// ---- prep: Et[d][k] = emb[k][d] (transposed fp32), hsq[k] = 0.5||e_k||^2, zero out[0]
__global__ void vq_prep(const float* __restrict__ emb, float* __restrict__ Et,
                        float* __restrict__ hsq, float* __restrict__ out)
{
    const int t = blockIdx.x * 256 + threadIdx.x;      // 0..16383
    if (t == 0) out[0] = 0.f;
    const int k = t & 1023, dg = t >> 10;              // code, dim-group of 4
    float4 v = ((const float4*)emb)[k * 16 + dg];      // emb[k][4dg..4dg+3]
    Et[(dg * 4 + 0) * 1024 + k] = v.x;                 // stores coalesced over k
    Et[(dg * 4 + 1) * 1024 + k] = v.y;
    Et[(dg * 4 + 2) * 1024 + k] = v.z;
    Et[(dg * 4 + 3) * 1024 + k] = v.w;
    if (t < NCODES) {
        const float4* r = (const float4*)(emb + (size_t)t * DIMS);
        float s = 0.f;
        #pragma unroll
        for (int i = 0; i < 16; ++i) {
            float4 e = r[i];
            s = fmaf(e.x, e.x, s); s = fmaf(e.y, e.y, s);
            s = fmaf(e.z, e.z, s); s = fmaf(e.w, e.w, s);
        }
        hsq[t] = 0.5f * s;
    }
}

__launch_bounds__(512, 4)
__global__ void vq_main(const float* __restrict__ in, const float* __restrict__ emb,
                        const float* __restrict__ Et, const float* __restrict__ hsqw,
                        float* __restrict__ out)
{
    __shared__ float cv[4][NPB];                       // per-quarter candidates
    __shared__ int   ci[4][NPB];
    __shared__ float lred[8];

    const int tid = threadIdx.x;
    const int lane = tid & 63, w = tid >> 6;
    const int p = tid & 127, q = tid >> 7;             // point-in-block, code-quarter (wave-uniform)
    const int n0 = blockIdx.x * NPB;
    const int b = n0 >> 12, off = n0 & 4095;           // 128 | 4096: never crosses a batch
    const float* xbase = in + (size_t)b * (DIMS * HW) + off;
    const float* xp = xbase + p;

    // ---- x in 16 float4 registers; ONLY static indexing from here on
    float4 xr[16];
    #pragma unroll
    for (int dg = 0; dg < 16; ++dg) {
        xr[dg].x = xp[(dg * 4 + 0) * HW];              // coalesced over the point-lanes
        xr[dg].y = xp[(dg * 4 + 1) * HW];
        xr[dg].z = xp[(dg * 4 + 2) * HW];
        xr[dg].w = xp[(dg * 4 + 3) * HW];
    }

    float v1 = 1e30f; int i1 = 0;

    // ---- this thread's 256 codes in 16 chunks of 16; SGPR base -> s_load for e/hsq
    const int kq = __builtin_amdgcn_readfirstlane(q * 256);
    for (int ch = 0; ch < 16; ++ch) {
        const int k0 = kq + ch * 16;
        const float* ebase = Et + k0;
        float acc[16];
        #pragma unroll
        for (int j = 0; j < 16; ++j) acc[j] = 0.f;

        #pragma unroll
        for (int dg = 0; dg < 16; ++dg) {              // 4 dims per block, e per-dim in flight
            const float4 xv = xr[dg];
            #pragma unroll
            for (int di = 0; di < 4; ++di) {
                const float4* er = (const float4*)(ebase + (dg * 4 + di) * 1024);
                const float4 e0 = er[0], e1 = er[1], e2 = er[2], e3 = er[3];
                const float xd = (di == 0) ? xv.x : (di == 1) ? xv.y : (di == 2) ? xv.z : xv.w;
                acc[ 0] = fmaf(xd, e0.x, acc[ 0]); acc[ 1] = fmaf(xd, e0.y, acc[ 1]);
                acc[ 2] = fmaf(xd, e0.z, acc[ 2]); acc[ 3] = fmaf(xd, e0.w, acc[ 3]);
                acc[ 4] = fmaf(xd, e1.x, acc[ 4]); acc[ 5] = fmaf(xd, e1.y, acc[ 5]);
                acc[ 6] = fmaf(xd, e1.z, acc[ 6]); acc[ 7] = fmaf(xd, e1.w, acc[ 7]);
                acc[ 8] = fmaf(xd, e2.x, acc[ 8]); acc[ 9] = fmaf(xd, e2.y, acc[ 9]);
                acc[10] = fmaf(xd, e2.z, acc[10]); acc[11] = fmaf(xd, e2.w, acc[11]);
                acc[12] = fmaf(xd, e3.x, acc[12]); acc[13] = fmaf(xd, e3.y, acc[13]);
                acc[14] = fmaf(xd, e3.z, acc[14]); acc[15] = fmaf(xd, e3.w, acc[15]);
            }
        }
        #pragma unroll
        for (int j = 0; j < 16; ++j) {                 // ascending k, strict <: first-min kept
            float dv = hsqw[k0 + j] - acc[j];
            if (dv < v1) { v1 = dv; i1 = k0 + j; }
        }
    }
    cv[q][p] = v1; ci[q][p] = i1;
    __syncthreads();

    // ---- merge the 4 quarters per point (ascending q = ascending code range)
    if (tid < NPB) {
        float bv = cv[0][tid]; int bi = ci[0][tid];
        #pragma unroll
        for (int qq = 1; qq < 4; ++qq) {
            float ov = cv[qq][tid]; int oi = ci[qq][tid];
            if (ov < bv) { bv = ov; bi = oi; }         // strict: earlier quarter wins ties
        }
        ci[0][tid] = bi;
    }
    __syncthreads();

    // ---- outputs: index, quantized gather-write, loss (512 threads: 16 dims each)
    //      x re-read from global (L2-hot) -> no dynamic register-array indexing
    {
        const int bi = ci[0][p];
        if (q == 0) out[IOFF + n0 + p] = (float)bi;
        const float* e = emb + (size_t)bi * DIMS + q * 16;
        const float* xq = xp + q * 16 * HW;
        float* oq = out + QOFF + (size_t)b * (DIMS * HW) + off + p + q * 16 * HW;
        float ls = 0.f;
        #pragma unroll
        for (int d0 = 0; d0 < 16; ++d0) {
            float ev = e[d0];                          // gather (L1/L2-hot 256 KB table)
            float xv = xq[d0 * HW];                    // coalesced re-read
            float df = ev - xv;
            ls = fmaf(df, df, ls);
            oq[d0 * HW] = ev;                          // coalesced over point-threads
        }
        #pragma unroll
        for (int st = 32; st; st >>= 1) ls += __shfl_down(ls, st);
        if (lane == 0) lred[w] = ls;
    }
    __syncthreads();
    if (tid == 0) {
        float s = 0.f;
        #pragma unroll
        for (int i = 0; i < 8; ++i) s += lred[i];
        atomicAdd(out, s * (0.25f / (float)(NPTS * DIMS)));
    }
}

extern "C" void kernel_launch(void* const* d_in, const int* in_sizes, int n_in,
                              void* d_out, int out_size, void* d_ws, size_t ws_size,
                              hipStream_t stream) {
    const float* in  = (const float*)d_in[0];
    const float* emb = (const float*)d_in[1];
    float* out = (float*)d_out;
    float* Et  = (float*)d_ws;                         // 262144 B (transposed table)
    float* hsq = (float*)((char*)d_ws + 262144);       // 4096 B
    (void)in_sizes; (void)n_in; (void)out_size; (void)ws_size;

    vq_prep<<<64, 256, 0, stream>>>(emb, Et, hsq, out);   // also zeroes out[0]
    vq_main<<<NPTS / NPB, 512, 0, stream>>>(in, emb, Et, hsq, out);
}

// Round 16
// 217.093 us; speedup vs baseline: 2.5109x; 1.0055x over previous
//
#include <hip/hip_runtime.h>

// VQ-VAE vector quantizer, round 16: pure-VALU exact-fp32; x in LDS, e on the SMEM pipe.
// R15 hit VALUBusy 76% but 2.3x VALU-instr bloat: compiler refused x[64] residency
// (VGPR=52) and re-loaded x from global per chunk + select chains. Fix: stop using a big
// register array at all.
//   - x: LDS, stride 65 ((p+d)%32 banks -> 2-way aliasing, free); one ds_read_b32 with
//     immediate offset per 16-FMA group (zero addressing VALU)
//   - e: Et[d][k] transposed table; k0 uniform via readfirstlane, d static -> s_load
//     (SMEM pipe, off VALU and off LDS - R1's LDS overload was the e-reads)
//   - acc[16]+track ~ 40 VGPR: nothing for the allocator to spill
//   - chunk loop rolled (code ~9KB, fits I$); d-loop unrolled inside
// Thread (p,q): point p, code-quarter [256q,256q+256). 512 thr/block, 512 blocks.
// Budget/CU: VALU 137k cyc/SIMD = 57us; LDS pipe 95k cyc; SMEM trivial. Target 60-80us.
// out (fp32 concat): [ loss(1) | quantized NCHW (4194304) | indices as float (65536) ]

#define DIMS   64
#define HW     4096
#define NPTS   65536
#define NCODES 1024
#define NPB    128                 // points per block (512 threads = 128 pts x 4 quarters)
#define XSTR   65                  // LDS x stride: (p*65+d)%32=(p+d)%32 -> 2-way max
#define QOFF   1
#define IOFF   (1 + NPTS * DIMS)

typedef unsigned int uint;

// ---- prep: Et[d][k] = emb[k][d] (transposed fp32), hsq[k] = 0.5||e_k||^2, zero out[0]
__global__ void vq_prep(const float* __restrict__ emb, float* __restrict__ Et,
                        float* __restrict__ hsq, float* __restrict__ out)
{
    const int t = blockIdx.x * 256 + threadIdx.x;      // 0..16383
    if (t == 0) out[0] = 0.f;
    const int k = t & 1023, dg = t >> 10;              // code, dim-group of 4
    float4 v = ((const float4*)emb)[k * 16 + dg];      // emb[k][4dg..4dg+3]
    Et[(dg * 4 + 0) * 1024 + k] = v.x;                 // stores coalesced over k
    Et[(dg * 4 + 1) * 1024 + k] = v.y;
    Et[(dg * 4 + 2) * 1024 + k] = v.z;
    Et[(dg * 4 + 3) * 1024 + k] = v.w;
    if (t < NCODES) {
        const float4* r = (const float4*)(emb + (size_t)t * DIMS);
        float s = 0.f;
        #pragma unroll
        for (int i = 0; i < 16; ++i) {
            float4 e = r[i];
            s = fmaf(e.x, e.x, s); s = fmaf(e.y, e.y, s);
            s = fmaf(e.z, e.z, s); s = fmaf(e.w, e.w, s);
        }
        hsq[t] = 0.5f * s;
    }
}

__launch_bounds__(512, 4)
__global__ void vq_main(const float* __restrict__ in, const float* __restrict__ emb,
                        const float* __restrict__ Et, const float* __restrict__ hsqw,
                        float* __restrict__ out)
{
    __shared__ float Xs[NPB * XSTR];                   // 33280 B
    __shared__ float cv[4][NPB];
    __shared__ int   ci[4][NPB];
    __shared__ float lred[8];

    const int tid = threadIdx.x;
    const int lane = tid & 63, w = tid >> 6;
    const int p = tid & 127, q = tid >> 7;             // point-in-block, quarter (wave-uniform)
    const int n0 = blockIdx.x * NPB;
    const int b = n0 >> 12, off = n0 & 4095;           // 128 | 4096: never crosses a batch
    const float* xbase = in + (size_t)b * (DIMS * HW) + off;

    // ---- stage X into LDS (each thread: 16 dims of its point; coalesced over p)
    {
        const float* xp = xbase + p;
        const int d0 = q * 16;
        #pragma unroll
        for (int i = 0; i < 16; ++i)
            Xs[p * XSTR + d0 + i] = xp[(d0 + i) * HW];
    }
    __syncthreads();

    float v1 = 1e30f; int i1 = 0;
    const int kq = __builtin_amdgcn_readfirstlane(q * 256);
    const float* xrow = Xs + p * XSTR;

    // ---- 16 chunks of 16 codes (rolled); d fully unrolled inside
    #pragma unroll 1
    for (int ch = 0; ch < 16; ++ch) {
        const int k0 = kq + ch * 16;
        const float* ebase = Et + k0;                  // uniform base -> s_load rows
        float acc[16];
        #pragma unroll
        for (int j = 0; j < 16; ++j) acc[j] = 0.f;

        #pragma unroll
        for (int d = 0; d < 64; ++d) {
            const float xd = xrow[d];                  // ds_read_b32, immediate offset
            const float4* er = (const float4*)(ebase + d * 1024);
            const float4 e0 = er[0], e1 = er[1], e2 = er[2], e3 = er[3];
            acc[ 0] = fmaf(xd, e0.x, acc[ 0]); acc[ 1] = fmaf(xd, e0.y, acc[ 1]);
            acc[ 2] = fmaf(xd, e0.z, acc[ 2]); acc[ 3] = fmaf(xd, e0.w, acc[ 3]);
            acc[ 4] = fmaf(xd, e1.x, acc[ 4]); acc[ 5] = fmaf(xd, e1.y, acc[ 5]);
            acc[ 6] = fmaf(xd, e1.z, acc[ 6]); acc[ 7] = fmaf(xd, e1.w, acc[ 7]);
            acc[ 8] = fmaf(xd, e2.x, acc[ 8]); acc[ 9] = fmaf(xd, e2.y, acc[ 9]);
            acc[10] = fmaf(xd, e2.z, acc[10]); acc[11] = fmaf(xd, e2.w, acc[11]);
            acc[12] = fmaf(xd, e3.x, acc[12]); acc[13] = fmaf(xd, e3.y, acc[13]);
            acc[14] = fmaf(xd, e3.z, acc[14]); acc[15] = fmaf(xd, e3.w, acc[15]);
        }
        #pragma unroll
        for (int j = 0; j < 16; ++j) {                 // ascending k, strict <: first-min kept
            float dv = hsqw[k0 + j] - acc[j];
            if (dv < v1) { v1 = dv; i1 = k0 + j; }
        }
    }
    cv[q][p] = v1; ci[q][p] = i1;
    __syncthreads();

    // ---- merge the 4 quarters per point (ascending q = ascending code range)
    if (tid < NPB) {
        float bv = cv[0][tid]; int bi = ci[0][tid];
        #pragma unroll
        for (int qq = 1; qq < 4; ++qq) {
            float ov = cv[qq][tid]; int oi = ci[qq][tid];
            if (ov < bv) { bv = ov; bi = oi; }         // strict: earlier quarter wins ties
        }
        ci[0][tid] = bi;
    }
    __syncthreads();

    // ---- outputs: index, quantized gather-write, loss (512 threads: 16 dims each);
    //      x read back from LDS (static offsets, no global re-read)
    {
        const int bi = ci[0][p];
        if (q == 0) out[IOFF + n0 + p] = (float)bi;
        const float* e = emb + (size_t)bi * DIMS + q * 16;
        float* oq = out + QOFF + (size_t)b * (DIMS * HW) + off + p + q * 16 * HW;
        const float* xr = xrow + q * 16;
        float ls = 0.f;
        #pragma unroll
        for (int d0 = 0; d0 < 16; ++d0) {
            float ev = e[d0];                          // gather (L1/L2-hot 256 KB table)
            float df = ev - xr[d0];
            ls = fmaf(df, df, ls);
            oq[d0 * HW] = ev;                          // coalesced over point-threads
        }
        #pragma unroll
        for (int st = 32; st; st >>= 1) ls += __shfl_down(ls, st);
        if (lane == 0) lred[w] = ls;
    }
    __syncthreads();
    if (tid == 0) {
        float s = 0.f;
        #pragma unroll
        for (int i = 0; i < 8; ++i) s += lred[i];
        atomicAdd(out, s * (0.25f / (float)(NPTS * DIMS)));
    }
}

extern "C" void kernel_launch(void* const* d_in, const int* in_sizes, int n_in,
                              void* d_out, int out_size, void* d_ws, size_t ws_size,
                              hipStream_t stream) {
    const float* in  = (const float*)d_in[0];
    const float* emb = (const float*)d_in[1];
    float* out = (float*)d_out;
    float* Et  = (float*)d_ws;                         // 262144 B (transposed table)
    float* hsq = (float*)((char*)d_ws + 262144);       // 4096 B
    (void)in_sizes; (void)n_in; (void)out_size; (void)ws_size;

    vq_prep<<<64, 256, 0, stream>>>(emb, Et, hsq, out);   // also zeroes out[0]
    vq_main<<<NPTS / NPB, 512, 0, stream>>>(in, emb, Et, hsq, out);
}

// Round 17
// 153.252 us; speedup vs baseline: 3.5568x; 1.4166x over previous
//
#include <hip/hip_runtime.h>

// VQ-VAE vector quantizer, FINAL (R17 = R12 consolidated): split-bf16 MFMA with explicit
// register double-buffer — the session-best structure (93.3us kernel / 155us bench).
// Session findings: MFMA variants are pinned at 93-103us regardless of tile shape, MFMA
// count (x4 range), chain depth, B-path (LDS vs global), barriers, or prefetch, with all
// pipes <20% busy (latency/clock regime, not expressible at HIP level); pure-VALU floor
// measured ~110-130us (R15/R16: VALUBusy ~75% at 163us). R12 wins.
// This round's only change vs R12: prep's hsq computed via 16-lane shuffle reduction over
// the float4s already loaded for bf16 conversion (removes the 1024-thread x 16-serial-load
// tail, ~4-8us of the prep launch).
// Kernel: 32x32x16 MFMA tiles, dot = xh.eh + xh.el + xl.eh (2 chains: hh 4-deep, hl+lh
// 8-deep), register double-buffered B (prefetch distance 1), exact streaming top-2 per
// lane, near-ties (gap < 1e-3 vs ~1e-4 split error) rescanned exactly in fp32.
// out (fp32 concat): [ loss(1) | quantized NCHW (4194304) | indices as float (65536) ]

#define DIMS   64
#define HW     4096
#define NPTS   65536
#define NCODES 1024
#define NPB    128
#define QOFF   1
#define IOFF   (1 + NPTS * DIMS)
#define EPSGAP 1.0e-3f

typedef unsigned int uint;
typedef unsigned short ushort;
typedef unsigned long long ull;
typedef __attribute__((ext_vector_type(8))) short short8;
typedef __attribute__((ext_vector_type(16))) float f32x16;

__device__ __forceinline__ ushort bf16_rne(float f) {
    uint u = __float_as_uint(f);
    uint r = u + 0x7FFFu + ((u >> 16) & 1u);
    return (ushort)(r >> 16);
}
__device__ __forceinline__ float bf16f(ushort h) { return __uint_as_float(((uint)h) << 16); }

// ---- prep: emb fp32 -> {Eh, El bf16 [1024][64]}, hsq = 0.5||e||^2 (shuffle), zero out[0]
__global__ void vq_prep(const float* __restrict__ emb, ushort* __restrict__ Eh,
                        ushort* __restrict__ El, float* __restrict__ hsq,
                        float* __restrict__ out)
{
    const int t = blockIdx.x * 256 + threadIdx.x;      // 0..16383 = code*16 + dim-group
    if (t == 0) out[0] = 0.f;
    float4 v = ((const float4*)emb)[t];
    ushort h0 = bf16_rne(v.x), h1 = bf16_rne(v.y), h2 = bf16_rne(v.z), h3 = bf16_rne(v.w);
    ushort l0 = bf16_rne(v.x - bf16f(h0)), l1 = bf16_rne(v.y - bf16f(h1));
    ushort l2 = bf16_rne(v.z - bf16f(h2)), l3 = bf16_rne(v.w - bf16f(h3));
    uint2 hp, lp;
    hp.x = (uint)h0 | ((uint)h1 << 16); hp.y = (uint)h2 | ((uint)h3 << 16);
    lp.x = (uint)l0 | ((uint)l1 << 16); lp.y = (uint)l2 | ((uint)l3 << 16);
    *(uint2*)(Eh + (size_t)t * 4) = hp;
    *(uint2*)(El + (size_t)t * 4) = lp;
    // hsq: 16 consecutive lanes hold one code's 16 float4s -> xor-shuffle reduce
    float pe = fmaf(v.x, v.x, fmaf(v.y, v.y, fmaf(v.z, v.z, v.w * v.w)));
    pe += __shfl_xor(pe, 1); pe += __shfl_xor(pe, 2);
    pe += __shfl_xor(pe, 4); pe += __shfl_xor(pe, 8);
    if ((t & 15) == 0) hsq[t >> 4] = 0.5f * pe;
}

__launch_bounds__(256, 2)
__global__ void vq_main(const float* __restrict__ in, const float* __restrict__ emb,
                        const ushort* __restrict__ Ehw, const ushort* __restrict__ Elw,
                        const float* __restrict__ hsqw, float* __restrict__ out)
{
    __shared__ float sv1[NPB];
    __shared__ float sv2[NPB];
    __shared__ int   si1[NPB];
    __shared__ ull   msk[2];
    __shared__ int   lst[1 + NPB];
    __shared__ float lred[4];

    const int tid = threadIdx.x;
    const int lane = tid & 63, w = tid >> 6;
    const int nn = lane & 31;                          // row (A) / col (B) within 32
    const int h  = lane >> 5;                          // k-half selector
    const int n0 = blockIdx.x * NPB;
    const int b = n0 >> 12, off = n0 & 4095;           // 128 | 4096: never crosses a batch
    const float* xbase = in + (size_t)b * (DIMS * HW) + off;

    // ---- A fragments: wave's 32 points, hi+lo bf16; k = ks*16 + 8h + j
    short8 Ah[4], Al[4];
    {
        const int p = w * 32 + nn;
        #pragma unroll
        for (int ks = 0; ks < 4; ++ks) {
            union { ushort u[8]; short8 v; } th, tl;
            #pragma unroll
            for (int j = 0; j < 8; ++j) {
                float x = xbase[(ks * 16 + h * 8 + j) * HW + p];
                ushort hh = bf16_rne(x);
                th.u[j] = hh;
                tl.u[j] = bf16_rne(x - bf16f(hh));
            }
            Ah[ks] = th.v; Al[ks] = tl.v;
        }
    }

    float v1s[16], v2s[16]; int i1s[16];
    #pragma unroll
    for (int r = 0; r < 16; ++r) { v1s[r] = 1e30f; v2s[r] = 1e30f; i1s[r] = 0; }

    auto loadB = [&](int g, short8 (&BH)[4], short8 (&BL)[4], float& HA) {
        const int ca = g * 32 + nn;
        const ushort* eb = Ehw + (size_t)ca * 64 + h * 8;
        const ushort* lb = Elw + (size_t)ca * 64 + h * 8;
        #pragma unroll
        for (int ks = 0; ks < 4; ++ks) {
            BH[ks] = *(const short8*)(eb + ks * 16);
            BL[ks] = *(const short8*)(lb + ks * 16);
        }
        HA = hsqw[ca];
    };

    auto compute = [&](int g, const short8 (&BH)[4], const short8 (&BL)[4], float HA) {
        f32x16 a1 = {0.f,0.f,0.f,0.f,0.f,0.f,0.f,0.f,0.f,0.f,0.f,0.f,0.f,0.f,0.f,0.f};
        f32x16 a2 = {0.f,0.f,0.f,0.f,0.f,0.f,0.f,0.f,0.f,0.f,0.f,0.f,0.f,0.f,0.f,0.f};
        #pragma unroll
        for (int ks = 0; ks < 4; ++ks)                 // chain 1: hh (4-deep)
            a1 = __builtin_amdgcn_mfma_f32_32x32x16_bf16(Ah[ks], BH[ks], a1, 0, 0, 0);
        #pragma unroll
        for (int ks = 0; ks < 4; ++ks)                 // chain 2a: hl
            a2 = __builtin_amdgcn_mfma_f32_32x32x16_bf16(Ah[ks], BL[ks], a2, 0, 0, 0);
        #pragma unroll
        for (int ks = 0; ks < 4; ++ks)                 // chain 2b: lh (same acc, 8-deep)
            a2 = __builtin_amdgcn_mfma_f32_32x32x16_bf16(Al[ks], BH[ks], a2, 0, 0, 0);
        const int ca = g * 32 + nn;
        #pragma unroll
        for (int r = 0; r < 16; ++r) {                 // r -> point row (fixed lane->code)
            float d = HA - (a1[r] + a2[r]);
            v2s[r] = fminf(v2s[r], fmaxf(d, v1s[r]));  // exact streaming 2nd-min
            bool c2 = d < v1s[r];                      // strict: ascending g keeps lowest idx
            i1s[r] = c2 ? ca : i1s[r];
            v1s[r] = fminf(d, v1s[r]);
        }
    };

    // ---- K-loop: 32 groups of 32 codes, register-double-buffered (prefetch distance 1)
    short8 BhA[4], BlA[4], BhB[4], BlB[4];
    float haA, haB;
    loadB(0, BhA, BlA, haA);
    for (int g = 0; g < 32; g += 2) {
        loadB(g + 1, BhB, BlB, haB);                   // in flight across compute(g)
        compute(g, BhA, BlA, haA);
        if (g + 2 < 32) loadB(g + 2, BhA, BlA, haA);   // in flight across compute(g+1)
        compute(g + 1, BhB, BlB, haB);
    }

    // ---- merge across the 32 code-lanes (both k-halves of a point share a half-wave)
    #pragma unroll
    for (int st = 1; st < 32; st <<= 1) {
        #pragma unroll
        for (int r = 0; r < 16; ++r) {
            float ov1 = __shfl_xor(v1s[r], st);
            float ov2 = __shfl_xor(v2s[r], st);
            int   oi1 = __shfl_xor(i1s[r], st);
            v2s[r] = fminf(fminf(v2s[r], ov2), fmaxf(v1s[r], ov1));
            bool c = (ov1 < v1s[r]) || (ov1 == v1s[r] && oi1 < i1s[r]);
            if (c) i1s[r] = oi1;
            v1s[r] = fminf(v1s[r], ov1);
        }
    }
    if (nn == 0) {                                     // lanes 0 and 32 hold 16 rows each
        #pragma unroll
        for (int r = 0; r < 16; ++r) {
            const int row = (r & 3) + 8 * (r >> 2) + 4 * h;
            const int p = w * 32 + row;
            sv1[p] = v1s[r]; si1[p] = i1s[r]; sv2[p] = v2s[r];
        }
    }
    __syncthreads();

    // ---- flag near-ties (waves 0,1 cover points 0..127)
    {
        bool f = (tid < NPB) && ((sv2[tid] - sv1[tid]) < EPSGAP);
        ull bm = __ballot(f);
        if (lane == 0 && w < 2) msk[w] = bm;
    }
    __syncthreads();
    if (tid == 0) {
        int c = 0;
        ull m0 = msk[0];
        while (m0) { lst[1 + c++] = __ffsll(m0) - 1; m0 &= m0 - 1; }
        ull m1 = msk[1];
        while (m1) { lst[1 + c++] = 64 + (__ffsll(m1) - 1); m1 &= m1 - 1; }
        lst[0] = c;
    }
    __syncthreads();

    // ---- exact fp32 rescan, one wave per flagged point (rare: gap < 1e-3)
    const int cnt = lst[0];
    const float4* e4 = (const float4*)emb;
    for (int it = w; it < cnt; it += 4) {
        const int p = lst[1 + it];
        float xv = xbase[lane * HW + p];               // lane d holds x_d (exact fp32)
        float bv = 1e30f; int bk = 0;
        #pragma unroll
        for (int half = 0; half < 2; ++half) {
            float dacc[8];
            #pragma unroll
            for (int j = 0; j < 8; ++j) dacc[j] = 0.f;
            for (int d4 = 0; d4 < 16; ++d4) {
                float x0 = __shfl(xv, d4 * 4 + 0), x1 = __shfl(xv, d4 * 4 + 1);
                float x2 = __shfl(xv, d4 * 4 + 2), x3 = __shfl(xv, d4 * 4 + 3);
                #pragma unroll
                for (int j = 0; j < 8; ++j) {
                    const int k = lane + 64 * (half * 8 + j);
                    float4 e = e4[k * 16 + d4];
                    dacc[j] = fmaf(x0, e.x, dacc[j]); dacc[j] = fmaf(x1, e.y, dacc[j]);
                    dacc[j] = fmaf(x2, e.z, dacc[j]); dacc[j] = fmaf(x3, e.w, dacc[j]);
                }
            }
            #pragma unroll
            for (int j = 0; j < 8; ++j) {              // ascending k per lane: first-min kept
                const int k = lane + 64 * (half * 8 + j);
                float v = hsqw[k] - dacc[j];
                if (v < bv) { bv = v; bk = k; }
            }
        }
        #pragma unroll
        for (int st = 32; st; st >>= 1) {              // 64-wide (v, k) argmin, k tie-break
            float ov = __shfl_xor(bv, st);
            int   ok = __shfl_xor(bk, st);
            if (ov < bv || (ov == bv && ok < bk)) { bv = ov; bk = ok; }
        }
        if (lane == 0) si1[p] = bk;
    }
    __syncthreads();

    // ---- final: indices, quantized gather-write, loss — all 256 threads (32 dims each)
    {
        const int p = tid & 127, dg = tid >> 7;
        const int bi = si1[p];
        if (dg == 0) out[IOFF + n0 + p] = (float)bi;
        const float* e = emb + (size_t)bi * DIMS;
        const float* xp = xbase + p;
        float* oq = out + QOFF + (size_t)b * (DIMS * HW) + off + p;
        float ls = 0.f;
        #pragma unroll
        for (int d0 = 0; d0 < 32; ++d0) {
            const int d = dg * 32 + d0;
            float ev = e[d];
            float xv = xp[d * HW];
            float df = ev - xv;
            ls = fmaf(df, df, ls);
            oq[d * HW] = ev;                           // coalesced across point-threads
        }
        #pragma unroll
        for (int st = 32; st; st >>= 1) ls += __shfl_down(ls, st);
        if (lane == 0) lred[w] = ls;
    }
    __syncthreads();
    if (tid == 0) {
        float s = lred[0] + lred[1] + lred[2] + lred[3];
        atomicAdd(out, s * (0.25f / (float)(NPTS * DIMS)));
    }
}

extern "C" void kernel_launch(void* const* d_in, const int* in_sizes, int n_in,
                              void* d_out, int out_size, void* d_ws, size_t ws_size,
                              hipStream_t stream) {
    const float* in  = (const float*)d_in[0];
    const float* emb = (const float*)d_in[1];
    float* out = (float*)d_out;
    ushort* Eh  = (ushort*)d_ws;                       // 131072 B
    ushort* El  = (ushort*)((char*)d_ws + 131072);     // 131072 B
    float*  hsq = (float*)((char*)d_ws + 262144);      // 4096 B
    (void)in_sizes; (void)n_in; (void)out_size; (void)ws_size;

    vq_prep<<<64, 256, 0, stream>>>(emb, Eh, El, hsq, out);   // also zeroes out[0]
    vq_main<<<NPTS / NPB, 256, 0, stream>>>(in, emb, Eh, El, hsq, out);
}